// Round 8
// baseline (275.691 us; speedup 1.0000x reference)
//
#include <hip/hip_runtime.h>
#include <hip/hip_bf16.h>

#define B_ 8
#define C_ 512
#define L_ 2048
#define G_ 32

typedef __attribute__((ext_vector_type(8))) short bf16x8;
typedef __attribute__((ext_vector_type(4))) float f32x4;

__device__ __forceinline__ short f2b(float f) {
    union { float f; unsigned u; } c; c.f = f;
    unsigned r = (c.u + 0x7FFFu + ((c.u >> 16) & 1u)) >> 16;
    return (short)r;
}

__device__ __forceinline__ void load_lds16(const void* g, void* s) {
    __builtin_amdgcn_global_load_lds(
        (const __attribute__((address_space(1))) void*)g,
        (__attribute__((address_space(3))) void*)s, 16, 0, 0);
}

// counted vmcnt wait + scheduling fence (rule #18: sched_barrier after asm wait)
template<int N>
__device__ __forceinline__ void wait_vm() {
    if constexpr (N == 0)      asm volatile("s_waitcnt vmcnt(0)" ::: "memory");
    else                       asm volatile("s_waitcnt vmcnt(8)" ::: "memory");
    __builtin_amdgcn_sched_barrier(0);
}
__device__ __forceinline__ void sbar() {
    __builtin_amdgcn_sched_barrier(0);
    __builtin_amdgcn_s_barrier();
    __builtin_amdgcn_sched_barrier(0);
}

// -------- convert 4 fp32 512x512 weights to bf16, concatenated --------
__global__ __launch_bounds__(256) void cvt_w(
    const float* __restrict__ a, const float* __restrict__ b,
    const float* __restrict__ c, const float* __restrict__ d,
    short* __restrict__ o)
{
    const float* src = (blockIdx.y == 0) ? a : (blockIdx.y == 1) ? b
                     : (blockIdx.y == 2) ? c : d;
    short* dst = o + (size_t)blockIdx.y * (C_ * C_);
    int i = (blockIdx.x * 256 + threadIdx.x) * 4;
    float4 v = *(const float4*)(src + i);
    short4 r;
    r.x = f2b(v.x); r.y = f2b(v.y); r.z = f2b(v.z); r.w = f2b(v.w);
    *(short4*)(dst + i) = r;
}

// -------- GroupNorm + transpose: x[b,c,l] fp32 -> h_t[b,l,c] bf16 --------
// Pass 1 reads x coalesced (float4) AND stages the 16x2048 fp32 slab in LDS;
// pass 2 normalizes+transposes out of LDS (no scattered global re-read of x).
// Pass 2 handles cl-pairs -> packed 4B stores. Also zeroes rowsum (64/block).
__global__ __launch_bounds__(256) void groupnorm_tr(
    const float* __restrict__ x, const float* __restrict__ gamma,
    const float* __restrict__ beta, short* __restrict__ h_t,
    float* __restrict__ rsum)
{
    __shared__ float xb[16][2052];          // 131,328 B -> 1 block/CU
    __shared__ float rs[4], rss[4], stats[2], gam[16], bet[16];
    int bg = blockIdx.x;
    int b = bg >> 5, g = bg & 31;
    const float* xg = x + ((size_t)b * C_ + (size_t)g * 16) * L_;  // 32768 floats
    int t = threadIdx.x;
    if (t < 64) rsum[(size_t)bg * 64 + t] = 0.f;
    float s = 0.f, ss = 0.f;
    #pragma unroll 4
    for (int i = t; i < 8192; i += 256) {
        float4 v = ((const float4*)xg)[i];
        int cl = i >> 9, l4 = (i & 511) << 2;
        *(float4*)&xb[cl][l4] = v;
        s  += v.x + v.y + v.z + v.w;
        ss += v.x * v.x + v.y * v.y + v.z * v.z + v.w * v.w;
    }
    #pragma unroll
    for (int o = 32; o > 0; o >>= 1) { s += __shfl_down(s, o); ss += __shfl_down(ss, o); }
    int wave = t >> 6, lane = t & 63;
    if (lane == 0) { rs[wave] = s; rss[wave] = ss; }
    if (t < 16) { gam[t] = gamma[g * 16 + t]; bet[t] = beta[g * 16 + t]; }
    __syncthreads();
    if (t == 0) {
        float S = rs[0] + rs[1] + rs[2] + rs[3];
        float SS = rss[0] + rss[1] + rss[2] + rss[3];
        float mean = S * (1.f / 32768.f);
        float var = SS * (1.f / 32768.f) - mean * mean;
        stats[0] = mean; stats[1] = rsqrtf(var + 1e-5f);
    }
    __syncthreads();
    float mean = stats[0], rstd = stats[1];
    short* ho = h_t + (size_t)b * L_ * C_ + (size_t)g * 16;
    for (int i = t; i < 16384; i += 256) {
        int cp = (i & 7) * 2, l = i >> 3;
        float a0 = (xb[cp][l]     - mean) * rstd * gam[cp]     + bet[cp];
        float a1 = (xb[cp + 1][l] - mean) * rstd * gam[cp + 1] + bet[cp + 1];
        unsigned pk = (unsigned)(unsigned short)f2b(a0)
                    | ((unsigned)(unsigned short)f2b(a1) << 16);
        *(unsigned*)(ho + (size_t)l * C_ + cp) = pk;
    }
}

// ===== fused QK^T+exp+rowsum  ||  V-projection  (one dispatch) ==============
// Both roles: 256x128 tile, PIPE=0 single-buffer (measured-best class: 48 KiB
// LDS -> 3 blocks/CU), 512 thr, K=512. 1-D grid of nb*160 blocks:
//   logical < nb*128 : QK   role (bx 0..15, by 0..7, bz)  S=exp2(a2*q.k), rowsum
//   else             : vproj role (bx 0..15, by 0..1, bz)  v_[c,l]=Wv.h^T+bv
// vproj blocks fill QK's tail; one launch boundary removed.
__global__ __launch_bounds__(512) void qk_vproj(
    const short* __restrict__ qk, const short* __restrict__ ht,
    const short* __restrict__ wv, short* __restrict__ S,
    short* __restrict__ v_, const float* __restrict__ bv,
    float* __restrict__ rsum, int nb, float alpha2)
{
    __shared__ __align__(16) short As[256 * 64];
    __shared__ __align__(16) short Bs[128 * 64];
    const int LC = L_ * C_;
    const size_t LL = (size_t)L_ * L_;

    int total = nb * 160;
    int lin = blockIdx.x;
    int chunk = total >> 3;                      // total % 8 == 0 always
    int logical = (lin & 7) * chunk + (lin >> 3);
    int qkN = nb << 7;
    bool isQK = logical < qkN;
    int bz, bx, by;
    if (isQK) { bz = logical >> 7; int rr = logical & 127; bx = rr & 15; by = rr >> 4; }
    else      { int r = logical - qkN; bz = r >> 5; int rr = r & 31; bx = rr & 15; by = rr >> 4; }

    int m0 = by * 256, n0 = bx * 128;
    int lda = isQK ? 1024 : 512;                 // ldb == lda for both roles
    const short* Ab = isQK ? qk + (size_t)bz * (2 * LC) : wv;
    const short* Bb = isQK ? qk + 512 + (size_t)bz * (2 * LC) : ht + (size_t)bz * LC;

    int t = threadIdx.x, lane = t & 63, wave = t >> 6;
    int wm = wave >> 1, wn = wave & 1;           // 4x2 wave grid, 64x64 tiles
    f32x4 acc[4][4] = {};

    int rs_ = t >> 3, cs_ = t & 7;
    int gcol = (cs_ ^ (rs_ & 7)) << 3;
    const short* gA = Ab + (size_t)(m0 + rs_) * lda + gcol;
    const short* gB = Bb + (size_t)(n0 + rs_) * lda + gcol;
    int fr = lane & 15, fq = lane >> 4;
    int ch0 = (fq ^ (fr & 7)) << 3, ch1 = ((4 | fq) ^ (fr & 7)) << 3;

    for (int k0 = 0; k0 < 512; k0 += 64) {
        __syncthreads();
        #pragma unroll
        for (int i = 0; i < 4; i++)              // A: 256 rows, 64 rows/pass
            load_lds16(gA + (size_t)(64 * i) * lda, As + i * 4096 + t * 8);
        #pragma unroll
        for (int i = 0; i < 2; i++)              // B: 128 rows
            load_lds16(gB + (size_t)(64 * i) * lda, Bs + i * 4096 + t * 8);
        gA += 64; gB += 64;
        __syncthreads();
        #pragma unroll
        for (int kk = 0; kk < 2; kk++) {
            int ch = kk ? ch1 : ch0;
            bf16x8 af[4], bfr[4];
            #pragma unroll
            for (int i = 0; i < 4; i++)
                af[i] = *(const bf16x8*)(As + (wm * 64 + i * 16 + fr) * 64 + ch);
            #pragma unroll
            for (int j = 0; j < 4; j++)
                bfr[j] = *(const bf16x8*)(Bs + (wn * 64 + j * 16 + fr) * 64 + ch);
            #pragma unroll
            for (int mt = 0; mt < 4; mt++)
                #pragma unroll
                for (int nt = 0; nt < 4; nt++)
                    acc[mt][nt] = __builtin_amdgcn_mfma_f32_16x16x32_bf16(
                        af[mt], bfr[nt], acc[mt][nt], 0, 0, 0);
        }
    }

    int crow = fq * 4, wrow = wm * 64;
    if (isQK) {
        short* Co = S + (size_t)bz * LL;
        float psum[4][4];
        #pragma unroll
        for (int mt = 0; mt < 4; mt++)
            #pragma unroll
            for (int r = 0; r < 4; r++) psum[mt][r] = 0.f;
        #pragma unroll
        for (int mt = 0; mt < 4; mt++) {
            #pragma unroll
            for (int nt = 0; nt < 4; nt++) {
                int n = n0 + wn * 64 + nt * 16 + fr;
                #pragma unroll
                for (int r = 0; r < 4; r++) {
                    int m = m0 + wrow + mt * 16 + crow + r;
                    float v = exp2f(acc[mt][nt][r] * alpha2);
                    psum[mt][r] += v;
                    Co[(size_t)m * L_ + n] = f2b(v);
                }
            }
        }
        #pragma unroll
        for (int mt = 0; mt < 4; mt++)
            #pragma unroll
            for (int r = 0; r < 4; r++) {
                float s = psum[mt][r];
                s += __shfl_xor(s, 1); s += __shfl_xor(s, 2);
                s += __shfl_xor(s, 4); s += __shfl_xor(s, 8);
                if ((lane & 15) == 0) {
                    int m = m0 + wrow + mt * 16 + crow + r;
                    atomicAdd(rsum + (size_t)bz * L_ + m, s);
                }
            }
    } else {
        short* Co = v_ + (size_t)bz * LC;
        #pragma unroll
        for (int mt = 0; mt < 4; mt++) {
            #pragma unroll
            for (int nt = 0; nt < 4; nt++) {
                int n = n0 + wn * 64 + nt * 16 + fr;
                #pragma unroll
                for (int r = 0; r < 4; r++) {
                    int m = m0 + wrow + mt * 16 + crow + r;
                    float v = acc[mt][nt][r] + bv[m];
                    Co[(size_t)m * L_ + n] = f2b(v);
                }
            }
        }
    }
}

// -------- bt-GEMM: BM x 128 tile, BK=64, XOR-swizzled LDS ----------------
// PIPE=0: single-buffer 2-barrier K-loop (best for BM=256 M=2048-class shapes).
// PIPE=1: dbuf + counted vmcnt (best for the BM=128 PV/outproj kernels).
template<int BM, int PIPE, int BIAS_MODE, bool RESID, bool OUTF32, bool ROWDIV>
__global__ __launch_bounds__(BM * 2) void gemm_bt(
    const short* __restrict__ A, const short* __restrict__ Bt,
    void* __restrict__ Co, const float* __restrict__ bias,
    const float* __restrict__ bias2, const float* __restrict__ resid,
    float* __restrict__ rowsum,
    int N, int K, int lda, int ldb, int ldc,
    long sA, long sB, long sC, float alpha)
{
    constexpr int T = BM * 2;
    constexpr int RPP = T / 8;
    constexpr int LPS = BM / RPP + 128 / RPP;
    constexpr int NBUF = (PIPE == 1) ? 2 : 1;
    __shared__ __align__(16) short As[NBUF][BM * 64];
    __shared__ __align__(16) short Bs[NBUF][128 * 64];

    int nbx = gridDim.x, nby = gridDim.y, nbz = gridDim.z;
    int lin = blockIdx.x + nbx * (blockIdx.y + nby * blockIdx.z);
    int total = nbx * nby * nbz;
    int bx, by, bz;
    if ((total & 7) == 0) {
        int chunk = total >> 3;
        int logical = (lin & 7) * chunk + (lin >> 3);
        bx = logical % nbx; int t2 = logical / nbx; by = t2 % nby; bz = t2 / nby;
    } else { bx = blockIdx.x; by = blockIdx.y; bz = blockIdx.z; }

    const short* Ab = A + (size_t)bz * sA;
    const short* Bb = Bt + (size_t)bz * sB;
    int m0 = by * BM, n0 = bx * 128;
    int t = threadIdx.x, lane = t & 63;
    int wave = t >> 6;
    int wm = wave >> 1, wn = wave & 1;

    f32x4 acc[4][4] = {};

    int rs_ = t >> 3, cs_ = t & 7;
    int gcol = ((cs_ ^ (rs_ & 7)) << 3);
    const short* gA = Ab + (size_t)(m0 + rs_) * lda + gcol;
    const short* gB = Bb + (size_t)(n0 + rs_) * ldb + gcol;
    int fr = lane & 15, fq = lane >> 4;
    int ch0 = (fq ^ (fr & 7)) << 3;
    int ch1 = ((4 | fq) ^ (fr & 7)) << 3;

    auto stage = [&](short* Asb, short* Bsb) {
        #pragma unroll
        for (int i = 0; i < BM / RPP; i++)
            load_lds16(gA + (size_t)(RPP * i) * lda, Asb + i * (RPP * 64) + t * 8);
        #pragma unroll
        for (int i = 0; i < 128 / RPP; i++)
            load_lds16(gB + (size_t)(RPP * i) * ldb, Bsb + i * (RPP * 64) + t * 8);
        gA += 64; gB += 64;
    };
    auto compute = [&](const short* Asb, const short* Bsb) {
        #pragma unroll
        for (int kk = 0; kk < 2; kk++) {
            int ch = kk ? ch1 : ch0;
            bf16x8 af[4], bfr[4];
            #pragma unroll
            for (int i = 0; i < 4; i++)
                af[i] = *(const bf16x8*)(Asb + (wm * 64 + i * 16 + fr) * 64 + ch);
            #pragma unroll
            for (int j = 0; j < 4; j++)
                bfr[j] = *(const bf16x8*)(Bsb + (wn * 64 + j * 16 + fr) * 64 + ch);
            #pragma unroll
            for (int mt = 0; mt < 4; mt++)
                #pragma unroll
                for (int nt = 0; nt < 4; nt++)
                    acc[mt][nt] = __builtin_amdgcn_mfma_f32_16x16x32_bf16(
                        af[mt], bfr[nt], acc[mt][nt], 0, 0, 0);
        }
    };

    if constexpr (PIPE == 0) {
        for (int k0 = 0; k0 < K; k0 += 64) {
            __syncthreads();
            stage(As[0], Bs[0]);
            __syncthreads();
            compute(As[0], Bs[0]);
        }
    } else {
        int nk = K >> 6;
        stage(As[0], Bs[0]);
        stage(As[1], Bs[1]);
        wait_vm<LPS>();
        sbar();
        for (int kt = 0; kt < nk; kt += 2) {
            compute(As[0], Bs[0]);
            sbar();
            if (kt + 2 < nk) { stage(As[0], Bs[0]); wait_vm<LPS>(); }
            else               wait_vm<0>();
            sbar();
            compute(As[1], Bs[1]);
            sbar();
            if (kt + 3 < nk) { stage(As[1], Bs[1]); wait_vm<LPS>(); }
            else               wait_vm<0>();
            sbar();
        }
    }

    size_t cb = (size_t)bz * sC;
    int crow = (lane >> 4) * 4;
    int wrow = wm * 64;
    float inv[4][4];
    if (ROWDIV) {
        #pragma unroll
        for (int mt = 0; mt < 4; mt++)
            #pragma unroll
            for (int r = 0; r < 4; r++) {
                int m = m0 + wrow + mt * 16 + crow + r;
                inv[mt][r] = 1.f / rowsum[(size_t)bz * L_ + m];
            }
    }
    #pragma unroll
    for (int mt = 0; mt < 4; mt++) {
        #pragma unroll
        for (int nt = 0; nt < 4; nt++) {
            int n = n0 + wn * 64 + nt * 16 + fr;
            float bn = 0.f;
            if (BIAS_MODE == 3) bn = (n < 512) ? bias[n] : bias2[n - 512];
            #pragma unroll
            for (int r = 0; r < 4; r++) {
                int m = m0 + wrow + mt * 16 + crow + r;
                float v = acc[mt][nt][r] * alpha;
                if (ROWDIV) v *= inv[mt][r];
                if (BIAS_MODE == 3) v += bn;
                if (BIAS_MODE == 2) v += bias[m];
                size_t idx = cb + (size_t)m * ldc + n;
                if (RESID) v += resid[idx];
                if (OUTF32) ((float*)Co)[idx] = v;
                else        ((short*)Co)[idx] = f2b(v);
            }
        }
    }
}

extern "C" void kernel_launch(void* const* d_in, const int* in_sizes, int n_in,
                              void* d_out, int out_size, void* d_ws, size_t ws_size,
                              hipStream_t stream)
{
    const float* x     = (const float*)d_in[0];
    const float* gamma = (const float*)d_in[1];
    const float* beta  = (const float*)d_in[2];
    const float* Wq    = (const float*)d_in[3];
    const float* bq    = (const float*)d_in[4];
    const float* Wk    = (const float*)d_in[5];
    const float* bk    = (const float*)d_in[6];
    const float* Wv    = (const float*)d_in[7];
    const float* bv    = (const float*)d_in[8];
    const float* Wo    = (const float*)d_in[9];
    const float* bo    = (const float*)d_in[10];
    float* out = (float*)d_out;

    const size_t MiB = 1024 * 1024;
    const size_t CC = (size_t)C_ * C_;
    const size_t LC = (size_t)L_ * C_;
    const size_t LL = (size_t)L_ * L_;
    const size_t wbytes = 4 * CC * sizeof(short);

    const size_t perb = 16 * MiB + L_ * sizeof(float);
    int nb = 1;
    for (int c = 8; c >= 1; c >>= 1)
        if (ws_size >= wbytes + (size_t)c * perb) { nb = c; break; }

    short* wq_b = (short*)d_ws;       // rows 0-511 Wq, 512-1023 Wk (contiguous)
    short* wv_b = wq_b + 2 * CC;
    short* wo_b = wv_b + CC;
    short* h_t  = wo_b + CC;
    short* qk_t = h_t + (size_t)nb * LC;
    short* v_   = qk_t + (size_t)nb * 2 * LC;
    short* S    = v_  + (size_t)nb * LC;
    float* rsum = (float*)(S + (size_t)nb * LL);
    short* a_t  = h_t;                              // h_t dead after qk_vproj

    const long sLC = (long)LC;
    const long sLL = (long)LL;
    // 1/sqrt(512) * log2(e): QK epilogue uses exp2
    const float alpha2 = 0.04419417382415922f * 1.4426950408889634f;

    cvt_w<<<dim3(C_ * C_ / 1024, 4), 256, 0, stream>>>(Wq, Wk, Wv, Wo, wq_b);

    for (int b0 = 0; b0 < B_; b0 += nb) {
        const float* xb = x + (size_t)b0 * LC;
        float* outb = out + (size_t)b0 * LC;

        groupnorm_tr<<<dim3(nb * G_), 256, 0, stream>>>(xb, gamma, beta, h_t, rsum);

        // qk_t[l, 0..1023] = h_t[l,:]·[Wq;Wk]^T + [bq;bk]   (BM=256 PIPE=0)
        gemm_bt<256, 0, 3, false, false, false><<<dim3(8, 8, nb), 512, 0, stream>>>(
            h_t, wq_b, qk_t, bq, bk, nullptr, nullptr,
            1024, 512, 512, 512, 1024, sLC, 0, 2 * sLC, 1.f);
        // fused: S = exp2(a2 * q.k), rowsum  ||  v_[c,l] = Wv·h^T + bv
        qk_vproj<<<dim3(nb * 160), 512, 0, stream>>>(
            qk_t, h_t, wv_b, S, v_, bv, rsum, nb, alpha2);
        // a_t[i,c] = (sum_j S[i,j] v[c,j]) / rowsum[i]
        gemm_bt<128, 1, 0, false, false, true><<<dim3(4, 16, nb), 256, 0, stream>>>(
            S, v_, a_t, nullptr, nullptr, nullptr, rsum,
            512, 2048, 2048, 2048, 512, sLL, sLC, sLC, 1.f);
        // out[c,l] = x[c,l] + bo[c] + Wo·a^T   (fp32 out)
        gemm_bt<128, 1, 2, true, true, false><<<dim3(16, 4, nb), 256, 0, stream>>>(
            wo_b, a_t, outb, bo, nullptr, xb, nullptr,
            2048, 512, 512, 512, 2048, 0, sLC, sLC, 1.f);
    }
}